// Round 6
// baseline (141.695 us; speedup 1.0000x reference)
//
#include <hip/hip_runtime.h>

#define T_DIM 512
#define B_DIM 128
#define E_DIM 256
#define NEG_INF (-1e30f)
#define CAP 28           // max staged (wt,m) entries per (b,t); fallback past this

typedef float vfloat4 __attribute__((ext_vector_type(4)));  // native vec for nt-store

// Closed-form stack math (exact max-plus identity):
//   rc_t[tau] = S[t] + max_{m in [tau,t]} g[m],  S = incl. prefix sum of (d-u),
//   g[m] = d[m] - S[m].
//   W[t][tau] != 0 only at right-to-left records of g (NGL chain from t),
//   truncated once S[t] + g[m] >= 1.
// R4 insight: the chain walk needs no v data -> do it in kernel 1 (all scalars
// in LDS), emit per-(b,t) weight lists; kernel 2 is then a pure gather with
// INDEPENDENT loads (no pointer chase on the v path).

struct Node { float g; int ngl; };   // g value + next-greater-to-left index

// Per-id list layout (256 B, 64 floats):
//   [0]=cnt (int bits, padded to multiple of 4, <=28)
//   [1]=cont_m (int bits, -1 if chain complete)
//   [2]=cont_prev, [3]=S
//   [4+2i]=wt_i, [5+2i]=m_i (int bits)   entries in chain order

// Kernel 1: per-b prep + chain walk. Shuffle wave-scan for S; sparse-table
// binary descend for NGL; then per-thread LDS walk emits the weight list.
__global__ void __launch_bounds__(512) scan_prep(
    const float* __restrict__ u, const float* __restrict__ d,
    float* __restrict__ lists, Node* __restrict__ nodes)
{
    const int b    = blockIdx.x;
    const int t    = threadIdx.x;
    const int lane = t & 63;
    const int w    = t >> 6;          // 8 waves

    __shared__ float wsum[8];
    __shared__ float wpre[8];
    __shared__ float M[10][T_DIM];    // M[k][i] = max g over [max(0,i-2^k+1), i]
    __shared__ int   sngl[T_DIM];

    const float dv = d[t * B_DIM + b];
    float x = dv - u[t * B_DIM + b];

    // wave-level inclusive scan (6 shfl steps)
    #pragma unroll
    for (int off = 1; off < 64; off <<= 1) {
        float y = __shfl_up(x, off, 64);
        if (lane >= off) x += y;
    }
    if (lane == 63) wsum[w] = x;
    __syncthreads();
    if (t < 8) {                       // tiny exclusive scan of 8 wave totals
        float s = 0.f;
        for (int i = 0; i < t; ++i) s += wsum[i];
        wpre[t] = s;
    }
    __syncthreads();
    const float S = x + wpre[w];       // inclusive prefix sum of (d-u)
    const float g = dv - S;

    // build sparse table: 9 levels of doubling window max (M[0] stays = g)
    M[0][t] = g;
    __syncthreads();
    #pragma unroll
    for (int k = 1; k < 10; ++k) {
        int h = 1 << (k - 1);
        float left = (t >= h) ? M[k - 1][t - h] : NEG_INF;
        float mk = fmaxf(M[k - 1][t], left);
        __syncthreads();               // level k-1 reads done
        M[k][t] = mk;
        __syncthreads();
    }

    // binary descend: largest m < t with g[m] > g (strict); else -1.
    int m = t - 1;
    #pragma unroll
    for (int k = 9; k >= 0; --k) {
        if (m >= 0 && M[k][m] <= g) m -= (1 << k);
    }
    if (m < 0) m = -1;

    const int id = (b << 9) | t;
    nodes[id] = Node{g, m};            // kept for kernel-2 overflow fallback
    sngl[t] = m;
    __syncthreads();

    // chain walk (all scalars in LDS): emit (wt, m) list in chain order.
    float* Lb = lists + (size_t)id * 64;
    float prev = 0.f;
    int   cm = t, cnt = 0, cont_m = -1;
    float cont_prev = 0.f;
    while (true) {
        const float gm = M[0][cm];
        const float rc = S + gm;
        const float cur = fminf(rc, 1.f);
        Lb[4 + 2 * cnt] = cur - prev;
        Lb[5 + 2 * cnt] = __int_as_float(cm);
        prev = cur;
        ++cnt;
        if (rc >= 1.f) break;
        const int nm = sngl[cm];
        if (nm < 0) break;
        cm = nm;
        if (cnt == CAP) { cont_m = cm; cont_prev = prev; break; }
    }
    // pad to multiple of 4 with wt=0 on the last (cache-hot) row
    const int last_m = cm;
    while (cnt & 3) {
        Lb[4 + 2 * cnt] = 0.f;
        Lb[5 + 2 * cnt] = __int_as_float(last_m);
        ++cnt;
    }
    Lb[0] = __int_as_float(cnt);
    Lb[1] = __int_as_float(cont_m);
    Lb[2] = cont_prev;
    Lb[3] = S;
}

// Kernel 2: pure gather. TWO ids per wave, XCD-chunked swizzle (consecutive
// ids share v rows -> per-XCD L2 residency). All v loads independent:
// per chunk = 2 uniform float4 list loads + 4 coalesced float4 row loads.
__global__ void __launch_bounds__(256) gather_read(
    const float* __restrict__ v, const float* __restrict__ lists,
    const Node* __restrict__ nodes, float* __restrict__ out)
{
    const int bid  = blockIdx.x;                       // 0..8191
    const int swz  = ((bid & 7) << 10) | (bid >> 3);   // XCD-chunked (8 XCDs)
    const int wid  = (swz << 2) | (threadIdx.x >> 6);  // 0..32767
    const int lane = threadIdx.x & 63;
    const int e4   = lane << 2;

    #pragma unroll
    for (int c = 0; c < 2; ++c) {
        const int id = (wid << 1) | c;
        const int b  = id >> 9, t = id & 511;
        const float* __restrict__ vb = v + (size_t)b * E_DIM + e4;  // + (m<<15)
        const float4* __restrict__ Lb = (const float4*)(lists + (size_t)id * 64);

        const float4 hdr = Lb[0];
        const int cnt    = __float_as_int(hdr.x);
        const int cont_m = __float_as_int(hdr.y);
        const int nch    = cnt >> 2;

        float4 acc = make_float4(0.f, 0.f, 0.f, 0.f);
        for (int ch = 0; ch < nch; ++ch) {
            const float4 q0 = Lb[1 + 2 * ch];
            const float4 q1 = Lb[2 + 2 * ch];
            const int ma = __float_as_int(q0.y);
            const int mb = __float_as_int(q0.w);
            const int mc = __float_as_int(q1.y);
            const int md = __float_as_int(q1.w);
            const float4 va = *(const float4*)(vb + ((size_t)ma << 15));
            const float4 vc2 = *(const float4*)(vb + ((size_t)mb << 15));
            const float4 vc3 = *(const float4*)(vb + ((size_t)mc << 15));
            const float4 vc4 = *(const float4*)(vb + ((size_t)md << 15));
            acc.x += q0.x * va.x + q0.z * vc2.x + q1.x * vc3.x + q1.z * vc4.x;
            acc.y += q0.x * va.y + q0.z * vc2.y + q1.x * vc3.y + q1.z * vc4.y;
            acc.z += q0.x * va.z + q0.z * vc2.z + q1.x * vc3.z + q1.z * vc4.z;
            acc.w += q0.x * va.w + q0.z * vc2.w + q1.x * vc3.w + q1.z * vc4.w;
        }

        if (cont_m >= 0) {             // overflow fallback (chain > CAP) — rare
            float prev = hdr.z;
            const float S = hdr.w;
            int m = cont_m;
            while (m >= 0) {
                const Node nd = nodes[(b << 9) | m];
                const float rc = S + nd.g;
                const float cur = fminf(rc, 1.f);
                const float wt = cur - prev; prev = cur;
                const float4 vv = *(const float4*)(vb + ((size_t)m << 15));
                acc.x += wt * vv.x; acc.y += wt * vv.y;
                acc.z += wt * vv.z; acc.w += wt * vv.w;
                if (rc >= 1.f) break;
                m = nd.ngl;
            }
        }

        const vfloat4 val = {acc.x, acc.y, acc.z, acc.w};
        __builtin_nontemporal_store(val,
            (vfloat4*)(out + ((size_t)t * B_DIM + b) * E_DIM + e4));
    }
}

extern "C" void kernel_launch(void* const* d_in, const int* in_sizes, int n_in,
                              void* d_out, int out_size, void* d_ws, size_t ws_size,
                              hipStream_t stream) {
    const float* v = (const float*)d_in[0];
    const float* u = (const float*)d_in[1];
    const float* d = (const float*)d_in[2];
    float* out = (float*)d_out;

    Node*  node  = (Node*)d_ws;                                   // 512 KB
    float* lists = (float*)((char*)d_ws + ((size_t)1 << 20));     // 16 MB @ +1MB

    scan_prep<<<dim3(B_DIM), 512, 0, stream>>>(u, d, lists, node);
    gather_read<<<dim3((T_DIM * B_DIM) / 8), 256, 0, stream>>>(v, lists, node, out);
}

// Round 7
// 131.665 us; speedup vs baseline: 1.0762x; 1.0762x over previous
//
#include <hip/hip_runtime.h>

#define T_DIM 512
#define B_DIM 128
#define E_DIM 256
#define NEG_INF (-1e30f)

typedef float vfloat4 __attribute__((ext_vector_type(4)));  // native vec for nt-store

// Closed-form stack math (exact max-plus identity):
//   rc_t[tau] = S[t] + max_{m in [tau,t]} g[m],  S = incl. prefix sum of (d-u),
//   g[m] = d[m] - S[m].
//   W[t][tau] != 0 only at right-to-left records of g (NGL chain from t),
//   truncated once S[t] + g[m] >= 1.
// R6 insight: time tracks total HBM bytes across all structures; the chase's
// residual inefficiency is cold-HBM latency on the serial chain (poison fills
// flush L3 every iteration). Fix: cooperative parallel v-warm of [t0-16,t0+7]
// per block -> chase loads become L1/L2 hits; v streams into L2 quasi-linearly.

struct Node { float g; int ngl; };   // g value + next-greater-to-left index

// Kernel 1: per-b prep. Shuffle wave-scan for S; sparse-table (range-max
// binary descend) for NGL: fixed 10 LDS probes per thread, no divergent scans.
__global__ void __launch_bounds__(512) scan_prep(
    const float* __restrict__ u, const float* __restrict__ d,
    float* __restrict__ S_out, Node* __restrict__ nodes)
{
    const int b    = blockIdx.x;
    const int t    = threadIdx.x;
    const int lane = t & 63;
    const int w    = t >> 6;          // 8 waves

    __shared__ float wsum[8];
    __shared__ float wpre[8];
    __shared__ float M[10][T_DIM];    // M[k][i] = max g over [max(0,i-2^k+1), i]

    const float dv = d[t * B_DIM + b];
    float x = dv - u[t * B_DIM + b];

    // wave-level inclusive scan (6 shfl steps)
    #pragma unroll
    for (int off = 1; off < 64; off <<= 1) {
        float y = __shfl_up(x, off, 64);
        if (lane >= off) x += y;
    }
    if (lane == 63) wsum[w] = x;
    __syncthreads();
    if (t < 8) {                       // tiny exclusive scan of 8 wave totals
        float s = 0.f;
        for (int i = 0; i < t; ++i) s += wsum[i];
        wpre[t] = s;
    }
    __syncthreads();
    const float S = x + wpre[w];       // inclusive prefix sum of (d-u)
    const float g = dv - S;

    // build sparse table: 9 levels of doubling window max
    M[0][t] = g;
    __syncthreads();
    #pragma unroll
    for (int k = 1; k < 10; ++k) {
        int h = 1 << (k - 1);
        float left = (t >= h) ? M[k - 1][t - h] : NEG_INF;
        float mk = fmaxf(M[k - 1][t], left);
        __syncthreads();               // level k-1 reads done
        M[k][t] = mk;
        __syncthreads();
    }

    // binary descend: largest m < t with g[m] > g (strict); else -1.
    int m = t - 1;
    #pragma unroll
    for (int k = 9; k >= 0; --k) {
        if (m >= 0 && M[k][m] <= g) m -= (1 << k);
    }
    if (m < 0) m = -1;

    S_out[(b << 9) | t] = S;
    nodes[(b << 9) | t] = Node{g, m};
}

// Kernel 2: TWO chains per wave + XCD-chunked swizzle (R4-proven best) +
// cooperative v-warm: 24 rows [t0-16, t0+7] of the block's b are fetched with
// fully independent loads BEFORE the chase, turning the chase's serial
// dependent loads into cache hits. Neighbor blocks (same XCD) warm the
// further-back rows.
__global__ void __launch_bounds__(256) stack_read(
    const float* __restrict__ v, const float* __restrict__ S_in,
    const Node* __restrict__ nodes, float* __restrict__ out)
{
    const int bid  = blockIdx.x;                       // 0..8191
    const int swz  = ((bid & 7) << 10) | (bid >> 3);   // XCD-chunked (8 XCDs)
    const int wv   = threadIdx.x >> 6;                 // wave in block 0..3
    const int wid  = (swz << 2) | wv;                  // 0..32767
    const int lane = threadIdx.x & 63;
    const int e4   = lane << 2;

    // block-level warm window: block ids = swz*8 .. swz*8+7 (same b, 8 t's)
    const int bb = (swz << 3) >> 9;                    // block's b (uniform)
    const int tb = (swz << 3) & 511;                   // block's first t
    {
        float4 wreg[6];
        #pragma unroll
        for (int i = 0; i < 6; ++i) {
            int r = tb - 16 + (i << 2) + wv;           // 4-wave stride covers 24 rows
            r = (r < 0) ? 0 : r;
            wreg[i] = *(const float4*)(v + ((size_t)r * B_DIM + bb) * E_DIM + e4);
        }
        float4 dm = wreg[0];
        #pragma unroll
        for (int i = 1; i < 6; ++i) {
            dm.x += wreg[i].x; dm.y += wreg[i].y;
            dm.z += wreg[i].z; dm.w += wreg[i].w;
        }
        asm volatile("" :: "v"(dm.x), "v"(dm.y), "v"(dm.z), "v"(dm.w));
    }

    const int id0  = wid << 1, id1 = id0 | 1;
    const int b0 = id0 >> 9, t0 = id0 & 511;
    const int b1 = id1 >> 9, t1 = id1 & 511;

    const float S0 = S_in[id0];
    const float S1 = S_in[id1];
    const Node* __restrict__ nb0 = nodes + (b0 << 9);
    const Node* __restrict__ nb1 = nodes + (b1 << 9);

    float4 acc0 = {0.f,0.f,0.f,0.f}, acc1 = {0.f,0.f,0.f,0.f};
    float prev0 = 0.f, prev1 = 0.f;
    int m0 = t0, m1 = t1;
    bool act0 = true, act1 = true;

    while (act0 || act1) {
        Node nd0, nd1; float4 vv0, vv1;
        if (act0) {
            nd0 = nb0[m0];
            vv0 = *(const float4*)(v + ((size_t)m0 * B_DIM + b0) * E_DIM + e4);
        }
        if (act1) {
            nd1 = nb1[m1];
            vv1 = *(const float4*)(v + ((size_t)m1 * B_DIM + b1) * E_DIM + e4);
        }
        if (act0) {
            float rc = S0 + nd0.g;
            float cur = fminf(rc, 1.f);
            float wt = cur - prev0;
            acc0.x += wt * vv0.x; acc0.y += wt * vv0.y;
            acc0.z += wt * vv0.z; acc0.w += wt * vv0.w;
            prev0 = cur;
            if (rc >= 1.f || nd0.ngl < 0) act0 = false; else m0 = nd0.ngl;
        }
        if (act1) {
            float rc = S1 + nd1.g;
            float cur = fminf(rc, 1.f);
            float wt = cur - prev1;
            acc1.x += wt * vv1.x; acc1.y += wt * vv1.y;
            acc1.z += wt * vv1.z; acc1.w += wt * vv1.w;
            prev1 = cur;
            if (rc >= 1.f || nd1.ngl < 0) act1 = false; else m1 = nd1.ngl;
        }
    }
    // Non-temporal stores: write-once stream, keep it out of L2/L3 so v rows
    // stay cache-resident.
    const vfloat4 o0 = {acc0.x, acc0.y, acc0.z, acc0.w};
    const vfloat4 o1 = {acc1.x, acc1.y, acc1.z, acc1.w};
    __builtin_nontemporal_store(o0,
        (vfloat4*)(out + ((size_t)t0 * B_DIM + b0) * E_DIM + e4));
    __builtin_nontemporal_store(o1,
        (vfloat4*)(out + ((size_t)t1 * B_DIM + b1) * E_DIM + e4));
}

extern "C" void kernel_launch(void* const* d_in, const int* in_sizes, int n_in,
                              void* d_out, int out_size, void* d_ws, size_t ws_size,
                              hipStream_t stream) {
    const float* v = (const float*)d_in[0];
    const float* u = (const float*)d_in[1];
    const float* d = (const float*)d_in[2];
    float* out = (float*)d_out;

    float* S    = (float*)d_ws;                                     // 256 KB
    Node*  node = (Node*)((char*)d_ws + (size_t)B_DIM * T_DIM * 4); // 512 KB

    scan_prep<<<dim3(B_DIM), 512, 0, stream>>>(u, d, S, node);
    stack_read<<<dim3((T_DIM * B_DIM) / 8), 256, 0, stream>>>(v, S, node, out);
}